// Round 1
// baseline (353.334 us; speedup 1.0000x reference)
//
#include <hip/hip_runtime.h>
#include <math.h>

#define NL 16
#define TS (1u << 19)
#define TMASK (TS - 1u)
#define PRIME 2654435761u

// Sort bins: g (1 bit) | iy_finest (9 bits) | ix_chunk (3 bits) = 8192 bins.
// Rationale: hash = ix ^ (iy*PRIME); x-adjacent corners share cache lines,
// y-adjacent corners jump randomly. Grouping by (g, row, x-chunk) confines a
// wave's fine-level gathers to ~0.5-4 KB table regions per level.
#define NBINS 8192
#define BIN_GBIT 12

struct ScalePack { float s[NL]; };

__device__ __forceinline__ unsigned bin_of(float px, float py, int g) {
    int iy = (int)(py * 511.0f); iy = iy < 0 ? 0 : (iy > 511 ? 511 : iy);
    int ix = (int)(px * 511.0f); ix = ix < 0 ? 0 : (ix > 511 ? 511 : ix);
    return ((unsigned)g << BIN_GBIT) | ((unsigned)iy << 3) | ((unsigned)ix >> 6);
}

__global__ __launch_bounds__(256)
void k_zero(unsigned* __restrict__ p, int n) {
    int i = blockIdx.x * blockDim.x + threadIdx.x;
    if (i < n) p[i] = 0u;
}

__global__ __launch_bounds__(256)
void k_hist(const float2* __restrict__ x, const int* __restrict__ hidx,
            unsigned* __restrict__ hist, int N)
{
    int n = blockIdx.x * blockDim.x + threadIdx.x;
    if (n >= N) return;
    float2 p = x[n];
    atomicAdd(&hist[bin_of(p.x, p.y, hidx[n])], 1u);
}

// Exclusive scan of NBINS u32, single block of 1024 threads, 8 bins/thread.
__global__ __launch_bounds__(1024)
void k_scan(const unsigned* __restrict__ hist, unsigned* __restrict__ offs)
{
    __shared__ unsigned partial[1024];
    int t = threadIdx.x;
    unsigned v[8];
    unsigned s = 0;
    #pragma unroll
    for (int i = 0; i < 8; ++i) { v[i] = hist[t * 8 + i]; s += v[i]; }
    partial[t] = s;
    __syncthreads();
    for (int d = 1; d < 1024; d <<= 1) {
        unsigned add = (t >= d) ? partial[t - d] : 0u;
        __syncthreads();
        partial[t] += add;
        __syncthreads();
    }
    unsigned base = (t == 0) ? 0u : partial[t - 1];
    #pragma unroll
    for (int i = 0; i < 8; ++i) { offs[t * 8 + i] = base; base += v[i]; }
}

__global__ __launch_bounds__(256)
void k_scatter(const float2* __restrict__ x, const int* __restrict__ hidx,
               unsigned* __restrict__ offs,
               float2* __restrict__ sxy, unsigned* __restrict__ smeta, int N)
{
    int n = blockIdx.x * blockDim.x + threadIdx.x;
    if (n >= N) return;
    float2 p = x[n];
    int g = hidx[n];
    unsigned b = bin_of(p.x, p.y, g);
    unsigned pos = atomicAdd(&offs[b], 1u);
    sxy[pos] = p;
    smeta[pos] = (unsigned)n | ((unsigned)g << 24);   // N < 16.7M fits 24 bits
}

__global__ __launch_bounds__(256)
void hashgrid2d_sorted(const float2* __restrict__ sxy,
                       const unsigned* __restrict__ smeta,
                       const float2* __restrict__ feat,
                       float4* __restrict__ out,
                       ScalePack sp, int N)
{
    // Bijective XCD-chunked swizzle: each XCD gets a contiguous range of the
    // sorted order (a y-band) so its private L2 owns that band's table rows.
    int nwg = gridDim.x;
    int orig = blockIdx.x;
    int q = nwg >> 3, r = nwg & 7;
    int xcd = orig & 7, loc = orig >> 3;
    int bid = (xcd < r ? xcd * (q + 1) : r * (q + 1) + (xcd - r) * q) + loc;

    int n = bid * 256 + (int)threadIdx.x;
    if (n >= N) return;

    float2 p = sxy[n];
    unsigned meta = smeta[n];
    int g  = (int)(meta >> 24);
    int no = (int)(meta & 0xFFFFFFu);
    float px = p.x, py = p.y;
    const float2* fb = feat + (size_t)g * ((size_t)NL * TS);

    float of[2 * NL];

    #pragma unroll 4
    for (int l = 0; l < NL; ++l) {
        float s  = sp.s[l];
        float fx = px * s;
        float fy = py * s;
        float fx0 = floorf(fx), fy0 = floorf(fy);
        float wx = fx - fx0, wy = fy - fy0;
        unsigned ix = (unsigned)(int)fx0;
        unsigned iy = (unsigned)(int)fy0;
        unsigned hy0 = iy * PRIME;
        unsigned hy1 = (iy + 1u) * PRIME;

        const float2* tab = fb + (size_t)l * TS;
        float2 c00 = tab[( ix       ^ hy0) & TMASK];
        float2 c10 = tab[((ix + 1u) ^ hy0) & TMASK];
        float2 c01 = tab[( ix       ^ hy1) & TMASK];
        float2 c11 = tab[((ix + 1u) ^ hy1) & TMASK];

        float w00 = (1.f - wx) * (1.f - wy);
        float w10 = wx * (1.f - wy);
        float w01 = (1.f - wx) * wy;
        float w11 = wx * wy;

        of[2 * l]     = w00 * c00.x + w10 * c10.x + w01 * c01.x + w11 * c11.x;
        of[2 * l + 1] = w00 * c00.y + w10 * c10.y + w01 * c01.y + w11 * c11.y;
    }

    float4* op = out + (size_t)no * 8;
    #pragma unroll
    for (int qq = 0; qq < 8; ++qq)
        op[qq] = make_float4(of[4 * qq], of[4 * qq + 1], of[4 * qq + 2], of[4 * qq + 3]);
}

// Fallback: the previously harness-verified direct kernel (no workspace).
__global__ __launch_bounds__(256)
void hashgrid2d_fwd(const float2* __restrict__ x,
                    const float2* __restrict__ feat,
                    const int* __restrict__ hidx,
                    float4* __restrict__ out,
                    ScalePack sp, int N)
{
    int n = blockIdx.x * blockDim.x + threadIdx.x;
    if (n >= N) return;

    float2 p = x[n];
    float px = p.x, py = p.y;
    int g = hidx[n];
    const float2* fb = feat + (size_t)g * ((size_t)NL * TS);

    float of[2 * NL];

    #pragma unroll 4
    for (int l = 0; l < NL; ++l) {
        float s  = sp.s[l];
        float fx = px * s;
        float fy = py * s;
        float fx0 = floorf(fx), fy0 = floorf(fy);
        float wx = fx - fx0, wy = fy - fy0;
        unsigned ix = (unsigned)(int)fx0;
        unsigned iy = (unsigned)(int)fy0;
        unsigned hy0 = iy * PRIME;
        unsigned hy1 = (iy + 1u) * PRIME;

        const float2* tab = fb + (size_t)l * TS;
        float2 c00 = tab[( ix       ^ hy0) & TMASK];
        float2 c10 = tab[((ix + 1u) ^ hy0) & TMASK];
        float2 c01 = tab[( ix       ^ hy1) & TMASK];
        float2 c11 = tab[((ix + 1u) ^ hy1) & TMASK];

        float w00 = (1.f - wx) * (1.f - wy);
        float w10 = wx * (1.f - wy);
        float w01 = (1.f - wx) * wy;
        float w11 = wx * wy;

        of[2 * l]     = w00 * c00.x + w10 * c10.x + w01 * c01.x + w11 * c11.x;
        of[2 * l + 1] = w00 * c00.y + w10 * c10.y + w01 * c01.y + w11 * c11.y;
    }

    float4* op = out + (size_t)n * 8;
    #pragma unroll
    for (int qq = 0; qq < 8; ++qq)
        op[qq] = make_float4(of[4 * qq], of[4 * qq + 1], of[4 * qq + 2], of[4 * qq + 3]);
}

extern "C" void kernel_launch(void* const* d_in, const int* in_sizes, int n_in,
                              void* d_out, int out_size, void* d_ws, size_t ws_size,
                              hipStream_t stream) {
    const float2* x    = (const float2*)d_in[0];   // fp32, (N,2)
    const float2* feat = (const float2*)d_in[1];   // fp32, (2,16,T,2)
    const int*    hidx = (const int*)d_in[2];      // int32, (N,1)
    int N = in_sizes[0] / 2;

    // Replicate reference _resolutions() exactly (double log/exp/pow, same
    // libm as CPython, truncating int()). Levels 3,6,9,12,15 are 1 ulp off
    // exact powers of two — do not hardcode.
    ScalePack sp;
    double b = exp((log(512.0) - log(16.0)) / 15.0);
    for (int i = 0; i < NL; ++i) {
        int r = (int)(16.0 * pow(b, (double)i));
        sp.s[i] = (float)(r - 1);
    }

    int threads = 256;
    int blocks = (N + threads - 1) / threads;

    size_t histB = (size_t)NBINS * 4;
    size_t offB  = (size_t)NBINS * 4;
    size_t xyB   = (size_t)N * 8;
    size_t metaB = (size_t)N * 4;
    size_t need  = histB + offB + xyB + metaB;   // ~12.06 MB at N=1e6

    if (d_ws != nullptr && ws_size >= need) {
        unsigned* hist  = (unsigned*)d_ws;
        unsigned* offs  = hist + NBINS;
        float2*   sxy   = (float2*)((char*)d_ws + histB + offB);      // 64KB off, 8-aligned
        unsigned* smeta = (unsigned*)((char*)d_ws + histB + offB + xyB);

        hipLaunchKernelGGL(k_zero, dim3((NBINS + 255) / 256), dim3(256), 0, stream,
                           hist, NBINS);
        hipLaunchKernelGGL(k_hist, dim3(blocks), dim3(threads), 0, stream,
                           x, hidx, hist, N);
        hipLaunchKernelGGL(k_scan, dim3(1), dim3(1024), 0, stream, hist, offs);
        hipLaunchKernelGGL(k_scatter, dim3(blocks), dim3(threads), 0, stream,
                           x, hidx, offs, sxy, smeta, N);
        hipLaunchKernelGGL(hashgrid2d_sorted, dim3(blocks), dim3(threads), 0, stream,
                           sxy, smeta, feat, (float4*)d_out, sp, N);
    } else {
        hipLaunchKernelGGL(hashgrid2d_fwd, dim3(blocks), dim3(threads), 0, stream,
                           x, feat, hidx, (float4*)d_out, sp, N);
    }
}